// Round 9
// baseline (209.711 us; speedup 1.0000x reference)
//
#include <hip/hip_runtime.h>

#define NTOK 2048
#define IN_DIM 1024
#define OUT_DIM 512
#define RNK 32
#define TG_N 32
#define TGK_N 128
#define AWCOLS 4096
#define KD 4224          // 4096 affine_w cols + 128 bias-indicator cols
#define SCALE_F 0.17677669529663687f

typedef __attribute__((ext_vector_type(8))) short short8;
typedef __attribute__((ext_vector_type(4))) float float4v;

__device__ __forceinline__ unsigned short f2bf(float f) {
  union { float f; unsigned int u; } c; c.f = f;
  unsigned int u = c.u;
  u += 0x7fffu + ((u >> 16) & 1u);   // round-to-nearest-even
  return (unsigned short)(u >> 16);
}

// k_w2t: 32x32 transpose tiles of [affine_w ; affine_b] -> bf16 W2t.
// 264 blocks x 8 tiles each (amortizes dispatch ramp vs 2112 blocks).
__global__ __launch_bounds__(256) void k_w2t(
    const float* __restrict__ aw, const float* __restrict__ ab,
    unsigned short* __restrict__ w2t) {
  __shared__ float tile[32][33];
  const int t = threadIdx.x;
  for (int tl = blockIdx.x; tl < 2112; tl += 264) {
    const int c0 = (tl % 132) * 32, o0 = (tl / 132) * 32;
    const int oo = t & 31, cc = t >> 5;  // cc 0..7
#pragma unroll
    for (int p = 0; p < 4; ++p) {
      int cidx = c0 + cc + p * 8;
      float v = (cidx < AWCOLS)
                    ? aw[(size_t)cidx * OUT_DIM + o0 + oo]
                    : ab[(size_t)(cidx - AWCOLS) * OUT_DIM + o0 + oo];
      tile[cc + p * 8][oo] = v;
    }
    __syncthreads();
    if (t < 128) {
      const int ol = t >> 2, ch = t & 3;  // 32 o-rows x 4 chunks of 8 cols
      union { short8 v; unsigned short u[8]; } pk;
#pragma unroll
      for (int j = 0; j < 8; ++j) pk.u[j] = f2bf(tile[ch * 8 + j][ol]);
      *(short8*)(w2t + (size_t)(o0 + ol) * KD + c0 + ch * 8) = pk.v;
    }
    __syncthreads();
  }
}

// k_zwin: 8 tokens/block (256 blocks) -- proj_w read once per block (33 MB
// total vs 134 MB at 2-tok). Math verbatim from R7's phase-1b (passed).
__global__ __launch_bounds__(256) void k_zwin(
    const float* __restrict__ x, const float* __restrict__ proj_w,
    const float* __restrict__ router_w, const float* __restrict__ router_b,
    unsigned short* __restrict__ zout, unsigned long long* __restrict__ wout) {
  const int tok8 = blockIdx.x * 8;
  const int t = threadIdx.x;
  __shared__ __align__(16) float zbuf[8][RNK];
  __shared__ float sc[8][TGK_N];
  __shared__ int winbuf[8][TG_N];

  const int r = t >> 3, c = t & 7;
  const float4* w4 = (const float4*)(proj_w + (size_t)r * IN_DIM);
  const float4* x0 = (const float4*)(x + (size_t)tok8 * IN_DIM);
  float acc[8] = {};
#pragma unroll
  for (int jj = 0; jj < 32; ++jj) {
    float4 wv = w4[jj * 8 + c];
#pragma unroll
    for (int tk = 0; tk < 8; ++tk) {
      float4 xv = x0[tk * 256 + jj * 8 + c];
      acc[tk] += xv.x * wv.x + xv.y * wv.y + xv.z * wv.z + xv.w * wv.w;
    }
  }
#pragma unroll
  for (int tk = 0; tk < 8; ++tk) {
    float a = acc[tk];
    a += __shfl_xor(a, 1); a += __shfl_xor(a, 2); a += __shfl_xor(a, 4);
    if (c == 0) zbuf[tk][r] = a;
  }
  __syncthreads();
  {
    const int cell = t & 127, th = t >> 7;
    const float4* rw = (const float4*)(router_w + (size_t)cell * RNK);
    const float rb = router_b[cell];
#pragma unroll
    for (int p = 0; p < 4; ++p) {
      const int tk = th + p * 2;  // th + {0,2,4,6}
      const float4* zb = (const float4*)(&zbuf[tk][0]);
      float s = rb;
#pragma unroll
      for (int j = 0; j < 8; ++j) {
        float4 a = rw[j]; float4 b = zb[j];
        s += a.x * b.x + a.y * b.y + a.z * b.z + a.w * b.w;
      }
      sc[tk][cell] = s;
    }
  }
  __syncthreads();
  {
    const int tk = t >> 5, tg = t & 31;  // 256 = 8 tokens x 32 groups
    float best = sc[tk][tg * 4]; int w = 0;
#pragma unroll
    for (int k = 1; k < 4; ++k) {
      float v = sc[tk][tg * 4 + k];
      if (v < best) { best = v; w = k; }
    }
    winbuf[tk][tg] = w;
    zout[(size_t)(tok8 + tk) * RNK + tg] = f2bf(zbuf[tk][tg]);  // tg doubles as r
  }
  __syncthreads();
  if (t < 8) {
    unsigned long long w = 0ull;
    for (int gg = 0; gg < TG_N; ++gg)
      w |= ((unsigned long long)(winbuf[t][gg] & 3)) << (2 * gg);
    wout[tok8 + t] = w;
  }
}

// k_gemm v6: barrier-cadence fix. Same math as v5 (R6/R8, passed), but each
// ring stage now carries 384 K-cols (6 x 64-chunks): 11 stages / 11 barriers
// instead of 66. Ring: 3 slots x 24 KB = 72 KB LDS. 6 DMAs/thread/stage;
// vmcnt(6) = stage st landed, stage st+1 in flight. Issue-after-barrier keeps
// slot reuse ordered. 128M x 32N per block, 256 blocks (1/CU), XCD-swizzled.
__global__ __launch_bounds__(256) void k_gemm(
    const unsigned short* __restrict__ z, const unsigned long long* __restrict__ win,
    const unsigned short* __restrict__ Bt, float* __restrict__ out) {
  __shared__ __align__(16) unsigned short Bs[3][6 * 2048];  // 3 slots x 6 subs x 4KB
  const int blk = blockIdx.x;
  const int g = blk & 7, rest = blk >> 3;        // XCD-aware decode
  const int bn = g * 2 + (rest & 1);             // 0..15
  const int bm = rest >> 1;                      // 0..15
  const int tid = threadIdx.x;
  const int wave = tid >> 6, lane = tid & 63;
  const int l15 = lane & 15, quad = lane >> 4;

  const int m0 = bm * 128 + wave * 32 + l15;
  const int m1 = m0 + 16;
  short8 z0 = *(const short8*)(z + (size_t)m0 * RNK + quad * 8);
  short8 z1 = *(const short8*)(z + (size_t)m1 * RNK + quad * 8);
  const unsigned long long w0 = win[m0], w1 = win[m1];

  const int sn = tid >> 3;
  const unsigned short* bsrc =
      Bt + (size_t)(bn * 32 + sn) * KD + (((tid & 7) ^ (sn & 7)) * 8);

  float4v acc00 = {}, acc01 = {}, acc10 = {}, acc11 = {};

  // issue all 6 sub-chunk DMAs of stage ST into slot ST%3
#define ISSUE6(ST)                                                               \
  _Pragma("unroll")                                                              \
  for (int j = 0; j < 6; ++j) {                                                  \
    __builtin_amdgcn_global_load_lds(                                            \
        (const __attribute__((address_space(1))) void*)(bsrc +                   \
            (size_t)((ST) * 6 + j) * 64),                                        \
        (__attribute__((address_space(3))) void*)(&Bs[(ST) % 3][j * 2048 +       \
            wave * 512]),                                                        \
        16, 0, 0);                                                               \
  }

  auto compute = [&](int kt, const unsigned short* sb) __attribute__((always_inline)) {
    const int fn0 = l15, fn1 = 16 + l15;
    if (kt < 64) {
      const int tg = kt >> 1;
      const unsigned e0 = (unsigned)(w0 >> (2 * tg)) & 3u;
      const unsigned e1 = (unsigned)(w1 >> (2 * tg)) & 3u;
#pragma unroll
      for (int s = 0; s < 2; ++s) {
        const unsigned kk = (unsigned)(((kt & 1) << 1) | s);
        short8 zz = {};
        short8 a0 = (e0 == kk) ? z0 : zz;
        short8 a1 = (e1 == kk) ? z1 : zz;
        short8 b0 = *(const short8*)(sb + fn0 * 64 + (((s * 4 + quad) ^ (fn0 & 7)) * 8));
        short8 b1 = *(const short8*)(sb + fn1 * 64 + (((s * 4 + quad) ^ (fn1 & 7)) * 8));
        acc00 = __builtin_amdgcn_mfma_f32_16x16x32_bf16(a0, b0, acc00, 0, 0, 0);
        acc01 = __builtin_amdgcn_mfma_f32_16x16x32_bf16(a0, b1, acc01, 0, 0, 0);
        acc10 = __builtin_amdgcn_mfma_f32_16x16x32_bf16(a1, b0, acc10, 0, 0, 0);
        acc11 = __builtin_amdgcn_mfma_f32_16x16x32_bf16(a1, b1, acc11, 0, 0, 0);
      }
    } else {
      // bias-indicator chunks (kt 64,65): one-hot bf16(1.0) at winner cell
#pragma unroll
      for (int s = 0; s < 2; ++s) {
        const int tgA = (kt - 64) * 16 + s * 8 + quad * 2;  // <= 30
        union { short8 v; unsigned long long q[2]; } fa, fb;
        fa.q[0] = 0x3F80ull << (((unsigned)(w0 >> (2 * tgA)) & 3u) * 16);
        fa.q[1] = 0x3F80ull << (((unsigned)(w0 >> (2 * (tgA + 1))) & 3u) * 16);
        fb.q[0] = 0x3F80ull << (((unsigned)(w1 >> (2 * tgA)) & 3u) * 16);
        fb.q[1] = 0x3F80ull << (((unsigned)(w1 >> (2 * (tgA + 1))) & 3u) * 16);
        short8 b0 = *(const short8*)(sb + fn0 * 64 + (((s * 4 + quad) ^ (fn0 & 7)) * 8));
        short8 b1 = *(const short8*)(sb + fn1 * 64 + (((s * 4 + quad) ^ (fn1 & 7)) * 8));
        acc00 = __builtin_amdgcn_mfma_f32_16x16x32_bf16(fa.v, b0, acc00, 0, 0, 0);
        acc01 = __builtin_amdgcn_mfma_f32_16x16x32_bf16(fa.v, b1, acc01, 0, 0, 0);
        acc10 = __builtin_amdgcn_mfma_f32_16x16x32_bf16(fb.v, b0, acc10, 0, 0, 0);
        acc11 = __builtin_amdgcn_mfma_f32_16x16x32_bf16(fb.v, b1, acc11, 0, 0, 0);
      }
    }
  };

  ISSUE6(0);
  ISSUE6(1);

  // stages 0..9: wait stage st (6 of next stage stay in flight), barrier,
  // issue st+2 (slot (st-1)%3 -- reads finished before this barrier), compute.
  for (int st = 0; st < 10; ++st) {
    asm volatile("s_waitcnt vmcnt(6)" ::: "memory");
    asm volatile("s_barrier" ::: "memory");
    if (st < 9) { ISSUE6(st + 2); }
#pragma unroll
    for (int j = 0; j < 6; ++j)
      compute(st * 6 + j, &Bs[st % 3][j * 2048]);
  }
  asm volatile("s_waitcnt vmcnt(0)" ::: "memory");
  asm volatile("s_barrier" ::: "memory");
#pragma unroll
  for (int j = 0; j < 6; ++j)
    compute(60 + j, &Bs[1][j * 2048]);  // stage 10 -> slot 10%3 = 1
#undef ISSUE6

  // epilogue: C/D layout col = lane&15, row = quad*4 + reg
#pragma unroll
  for (int tm = 0; tm < 2; ++tm) {
#pragma unroll
    for (int tn = 0; tn < 2; ++tn) {
      float4v a = tm ? (tn ? acc11 : acc10) : (tn ? acc01 : acc00);
      const int col = bn * 32 + tn * 16 + l15;
      const int rowb = bm * 128 + wave * 32 + tm * 16 + quad * 4;
#pragma unroll
      for (int rg = 0; rg < 4; ++rg)
        out[(size_t)(rowb + rg) * OUT_DIM + col] = a[rg] * SCALE_F;
    }
  }
}

extern "C" void kernel_launch(void* const* d_in, const int* in_sizes, int n_in,
                              void* d_out, int out_size, void* d_ws, size_t ws_size,
                              hipStream_t stream) {
  const float* x        = (const float*)d_in[0];
  const float* proj_w   = (const float*)d_in[1];
  const float* router_w = (const float*)d_in[2];
  const float* router_b = (const float*)d_in[3];
  const float* affine_w = (const float*)d_in[4];
  const float* affine_b = (const float*)d_in[5];
  float* out = (float*)d_out;

  unsigned short* zout = (unsigned short*)d_ws;                            // 128 KB
  unsigned long long* wout = (unsigned long long*)((char*)d_ws + 131072);  // 16 KB
  unsigned short* w2t = (unsigned short*)((char*)d_ws + 147456);           // 4.33 MB

  k_w2t<<<264, 256, 0, stream>>>(affine_w, affine_b, w2t);
  k_zwin<<<NTOK / 8, 256, 0, stream>>>(x, proj_w, router_w, router_b, zout, wout);
  k_gemm<<<256, 256, 0, stream>>>(zout, wout, w2t, out);
}